// Round 1
// baseline (330.600 us; speedup 1.0000x reference)
//
#include <hip/hip_runtime.h>

#define T_DIM 8192
#define D_DIM 1024
#define H_DIM 2048
#define N_DIM 4096
#define CHUNK 64
#define NCH   (T_DIM / CHUNK)   // 128

typedef __attribute__((ext_vector_type(8))) short bf16x8;
typedef __attribute__((ext_vector_type(4))) float f32x4;

// ---------------- helpers ----------------

__device__ __forceinline__ unsigned short f2bf(float f) {
    unsigned int u = __float_as_uint(f);
    unsigned int r = (u + 0x7fffu + ((u >> 16) & 1u)) >> 16;  // RNE
    return (unsigned short)r;
}

__device__ __forceinline__ void gl_lds16(const unsigned short* g, unsigned short* l) {
    __builtin_amdgcn_global_load_lds(
        (__attribute__((address_space(1))) void*)(g),
        (__attribute__((address_space(3))) void*)(l), 16, 0, 0);
}

// ---------------- kernel 1: per-channel params ----------------

__global__ void params_kernel(const float* __restrict__ lamda,
                              const float* __restrict__ theta,
                              float* __restrict__ pa, float* __restrict__ pb,
                              float* __restrict__ pg) {
    int h = blockIdx.x * 256 + threadIdx.x;
    if (h >= H_DIM) return;
    float y = expf(-expf(lamda[h]));
    float z = expf(theta[h]);
    pg[h] = sqrtf(1.0f - y * y);
    pa[h] = y * cosf(z);
    pb[h] = y * sinf(z);
}

// ---------------- kernel 2: fp32 -> bf16 convert ----------------

__global__ void cvt_kernel(const float4* __restrict__ s, ushort4* __restrict__ d, int n4) {
    int i = blockIdx.x * 256 + threadIdx.x;
    if (i >= n4) return;
    float4 f = s[i];
    ushort4 o;
    o.x = f2bf(f.x); o.y = f2bf(f.y); o.z = f2bf(f.z); o.w = f2bf(f.w);
    d[i] = o;
}

// ---------------- kernel 3: bf16 GEMM (A[M,K] x B[N,K]^T), gamma epilogue ----------------
// 128x128 tile, BK=32, 256 threads = 4 waves (2x2), each wave 64x64 via 4x4 MFMA 16x16x32.

__global__ __launch_bounds__(256) void gemm_bt(
    const unsigned short* __restrict__ A,   // [8192,1024] bf16
    const unsigned short* __restrict__ B,   // [4096,1024] bf16
    const float* __restrict__ gamma,        // [2048]
    float* __restrict__ C)                  // [8192,4096] fp32
{
    __shared__ unsigned short sA[128 * 32];  // 8 KB
    __shared__ unsigned short sB[128 * 32];  // 8 KB

    const int tid  = threadIdx.x;
    const int lane = tid & 63;
    const int wave = tid >> 6;
    const int quad = lane >> 4;
    const int m16  = lane & 15;
    const int wm = (wave >> 1) << 6;   // 0 or 64
    const int wn = (wave & 1) << 6;

    const int rowA0 = blockIdx.x * 128;
    const int rowB0 = blockIdx.y * 128;

    // staging map: thread t covers flat tile elems [8t,8t+8) (call0) and [2048+8t,..) (call1)
    const int e0 = tid * 8;
    const int r0 = e0 >> 5;            // row in tile (BK=32)
    const int k0 = e0 & 31;
    const int r1 = r0 + 64;            // second half

    const unsigned short* a0 = A + (size_t)(rowA0 + r0) * D_DIM + k0;
    const unsigned short* a1 = A + (size_t)(rowA0 + r1) * D_DIM + k0;
    const unsigned short* b0 = B + (size_t)(rowB0 + r0) * D_DIM + k0;
    const unsigned short* b1 = B + (size_t)(rowB0 + r1) * D_DIM + k0;
    unsigned short* la0 = &sA[e0];
    unsigned short* la1 = &sA[e0 + 2048];
    unsigned short* lb0 = &sB[e0];
    unsigned short* lb1 = &sB[e0 + 2048];

    f32x4 acc[4][4];
#pragma unroll
    for (int i = 0; i < 4; i++)
#pragma unroll
        for (int j = 0; j < 4; j++) acc[i][j] = (f32x4)(0.0f);

    for (int kt = 0; kt < D_DIM; kt += 32) {
        __syncthreads();                       // prev-tile reads done
        gl_lds16(a0 + kt, la0);
        gl_lds16(a1 + kt, la1);
        gl_lds16(b0 + kt, lb0);
        gl_lds16(b1 + kt, lb1);
        __syncthreads();                       // staging visible (vmcnt drained)

        bf16x8 af[4], bfr[4];
#pragma unroll
        for (int i = 0; i < 4; i++)
            af[i] = *(const bf16x8*)&sA[(wm + i * 16 + m16) * 32 + quad * 8];
#pragma unroll
        for (int i = 0; i < 4; i++)
            bfr[i] = *(const bf16x8*)&sB[(wn + i * 16 + m16) * 32 + quad * 8];

#pragma unroll
        for (int mi = 0; mi < 4; mi++)
#pragma unroll
            for (int ni = 0; ni < 4; ni++)
                acc[mi][ni] = __builtin_amdgcn_mfma_f32_16x16x32_bf16(
                    af[mi], bfr[ni], acc[mi][ni], 0, 0, 0);
    }

    // epilogue: C/D layout col=lane&15, row=quad*4+reg
#pragma unroll
    for (int ni = 0; ni < 4; ni++) {
        const int col = rowB0 + wn + ni * 16 + m16;
        const float g = gamma[col & (H_DIM - 1)];
#pragma unroll
        for (int mi = 0; mi < 4; mi++) {
            const int row0 = rowA0 + wm + mi * 16 + quad * 4;
#pragma unroll
            for (int r = 0; r < 4; r++)
                C[(size_t)(row0 + r) * N_DIM + col] = acc[mi][ni][r] * g;
        }
    }
}

// ---------------- kernel 4a: chunk-local end states (zero init) ----------------

__global__ void scanA(const float* __restrict__ v,       // d_out [T, 4096]
                      const float* __restrict__ pa, const float* __restrict__ pb,
                      float* __restrict__ E)             // [NCH][2][H]
{
    int h = blockIdx.x * 256 + threadIdx.x;   // 0..2047
    int c = blockIdx.y;                        // 0..NCH-1
    float a = pa[h], b = pb[h];
    float h1 = 0.f, h2 = 0.f;
    const float* p = v + (size_t)c * CHUNK * N_DIM + h;
#pragma unroll 8
    for (int t = 0; t < CHUNK; t++) {
        float v1 = p[0], v2 = p[H_DIM];
        float n1 = a * h1 - b * h2 + v1;
        float n2 = a * h2 + b * h1 + v2;
        h1 = n1; h2 = n2;
        p += N_DIM;
    }
    E[(size_t)c * N_DIM + h]        = h1;
    E[(size_t)c * N_DIM + H_DIM + h] = h2;
}

// ---------------- kernel 4b: scan carries across chunks ----------------

__global__ void scanB(const float* __restrict__ pa, const float* __restrict__ pb,
                      const float* __restrict__ E, float* __restrict__ P) {
    int h = blockIdx.x * 256 + threadIdx.x;
    float a = pa[h], b = pb[h];
    // w^CHUNK via log2(CHUNK)=6 complex squarings
    float wr = a, wi = b;
#pragma unroll
    for (int i = 0; i < 6; i++) {
        float nr = wr * wr - wi * wi;
        float ni = 2.f * wr * wi;
        wr = nr; wi = ni;
    }
    float p1 = 0.f, p2 = 0.f;
    for (int c = 0; c < NCH; c++) {
        P[(size_t)c * N_DIM + h]         = p1;
        P[(size_t)c * N_DIM + H_DIM + h] = p2;
        float e1 = E[(size_t)c * N_DIM + h];
        float e2 = E[(size_t)c * N_DIM + H_DIM + h];
        float n1 = wr * p1 - wi * p2 + e1;
        float n2 = wr * p2 + wi * p1 + e2;
        p1 = n1; p2 = n2;
    }
}

// ---------------- kernel 4c: final scan with carry-in, in-place ----------------

__global__ void scanC(float* __restrict__ v,             // d_out, in/out
                      const float* __restrict__ pa, const float* __restrict__ pb,
                      const float* __restrict__ P) {
    int h = blockIdx.x * 256 + threadIdx.x;
    int c = blockIdx.y;
    float a = pa[h], b = pb[h];
    float h1 = P[(size_t)c * N_DIM + h];
    float h2 = P[(size_t)c * N_DIM + H_DIM + h];
    float* p = v + (size_t)c * CHUNK * N_DIM + h;
#pragma unroll 8
    for (int t = 0; t < CHUNK; t++) {
        float v1 = p[0], v2 = p[H_DIM];
        float n1 = a * h1 - b * h2 + v1;
        float n2 = a * h2 + b * h1 + v2;
        h1 = n1; h2 = n2;
        p[0] = h1; p[H_DIM] = h2;
        p += N_DIM;
    }
}

// ---------------- launcher ----------------

extern "C" void kernel_launch(void* const* d_in, const int* in_sizes, int n_in,
                              void* d_out, int out_size, void* d_ws, size_t ws_size,
                              hipStream_t stream) {
    const float* x     = (const float*)d_in[0];   // [T, D]
    const float* lamda = (const float*)d_in[1];   // [H]
    const float* theta = (const float*)d_in[2];   // [H]
    const float* B1    = (const float*)d_in[3];   // [H, D]
    const float* B2    = (const float*)d_in[4];   // [H, D]
    float* out = (float*)d_out;                   // [T, 2H]

    char* ws = (char*)d_ws;
    unsigned short* xb = (unsigned short*)ws;                              // 16 MB
    unsigned short* Bb = (unsigned short*)(ws + (size_t)16 * 1024 * 1024); // 8 MB
    float* pa = (float*)(ws + (size_t)24 * 1024 * 1024);
    float* pb = pa + H_DIM;
    float* pg = pb + H_DIM;
    float* E  = pg + H_DIM;                    // NCH*4096 floats = 2 MB
    float* P  = E + (size_t)NCH * N_DIM;       // 2 MB

    // 1. params
    hipLaunchKernelGGL(params_kernel, dim3(H_DIM / 256), dim3(256), 0, stream,
                       lamda, theta, pa, pb, pg);
    // 2. converts
    hipLaunchKernelGGL(cvt_kernel, dim3((T_DIM * D_DIM / 4) / 256), dim3(256), 0, stream,
                       (const float4*)x, (ushort4*)xb, T_DIM * D_DIM / 4);
    hipLaunchKernelGGL(cvt_kernel, dim3((H_DIM * D_DIM / 4) / 256), dim3(256), 0, stream,
                       (const float4*)B1, (ushort4*)Bb, H_DIM * D_DIM / 4);
    hipLaunchKernelGGL(cvt_kernel, dim3((H_DIM * D_DIM / 4) / 256), dim3(256), 0, stream,
                       (const float4*)B2, (ushort4*)(Bb + (size_t)H_DIM * D_DIM),
                       H_DIM * D_DIM / 4);
    // 3. GEMM: v (gamma-scaled) straight into d_out
    hipLaunchKernelGGL(gemm_bt, dim3(T_DIM / 128, N_DIM / 128), dim3(256), 0, stream,
                       xb, Bb, pg, out);
    // 4. chunked scan
    hipLaunchKernelGGL(scanA, dim3(H_DIM / 256, NCH), dim3(256), 0, stream, out, pa, pb, E);
    hipLaunchKernelGGL(scanB, dim3(H_DIM / 256), dim3(256), 0, stream, pa, pb, E, P);
    hipLaunchKernelGGL(scanC, dim3(H_DIM / 256, NCH), dim3(256), 0, stream, out, pa, pb, P);
}

// Round 2
// 328.637 us; speedup vs baseline: 1.0060x; 1.0060x over previous
//
#include <hip/hip_runtime.h>

#define T_DIM 8192
#define D_DIM 1024
#define H_DIM 2048
#define N_DIM 4096
#define CHUNK 64
#define NCH   (T_DIM / CHUNK)   // 128

typedef __attribute__((ext_vector_type(8))) short bf16x8;
typedef __attribute__((ext_vector_type(4))) float f32x4;

// ---------------- helpers ----------------

__device__ __forceinline__ unsigned short f2bf(float f) {
    unsigned int u = __float_as_uint(f);
    unsigned int r = (u + 0x7fffu + ((u >> 16) & 1u)) >> 16;  // RNE
    return (unsigned short)r;
}

__device__ __forceinline__ float bf2f(unsigned short u) {
    return __uint_as_float((unsigned int)u << 16);
}

__device__ __forceinline__ void gl_lds16(const unsigned short* g, unsigned short* l) {
    __builtin_amdgcn_global_load_lds(
        (__attribute__((address_space(1))) void*)(g),
        (__attribute__((address_space(3))) void*)(l), 16, 0, 0);
}

// ---------------- kernel 1: per-channel params ----------------

__global__ void params_kernel(const float* __restrict__ lamda,
                              const float* __restrict__ theta,
                              float* __restrict__ pa, float* __restrict__ pb,
                              float* __restrict__ pg) {
    int h = blockIdx.x * 256 + threadIdx.x;
    if (h >= H_DIM) return;
    float y = expf(-expf(lamda[h]));
    float z = expf(theta[h]);
    pg[h] = sqrtf(1.0f - y * y);
    pa[h] = y * cosf(z);
    pb[h] = y * sinf(z);
}

// ---------------- kernel 2: fused fp32 -> bf16 convert (x, B1, B2 in one launch) ----------------

__global__ void cvt3_kernel(const float4* __restrict__ s0, ushort4* __restrict__ d0, int n0,
                            const float4* __restrict__ s1, ushort4* __restrict__ d1, int n1,
                            const float4* __restrict__ s2, ushort4* __restrict__ d2, int n2) {
    int i = blockIdx.x * 256 + threadIdx.x;
    const float4* s; ushort4* d; int j;
    if (i < n0)                { s = s0; d = d0; j = i; }
    else if (i < n0 + n1)      { s = s1; d = d1; j = i - n0; }
    else if (i < n0 + n1 + n2) { s = s2; d = d2; j = i - n0 - n1; }
    else return;
    float4 f = s[j];
    ushort4 o;
    o.x = f2bf(f.x); o.y = f2bf(f.y); o.z = f2bf(f.z); o.w = f2bf(f.w);
    d[j] = o;
}

// ---------------- kernel 3: bf16 GEMM (A[M,K] x B[N,K]^T), gamma epilogue ----------------
// 128x128 tile, BK=32, 256 threads = 4 waves (2x2), each wave 64x64 via 4x4 MFMA 16x16x32.
// LDS k-group XOR-swizzled by ((row>>1)&3) to break bank conflicts; since global_load_lds
// forces LDS slot = lane*16, the swizzle is applied to the GLOBAL source k-group.

template <bool BF16OUT>
__global__ __launch_bounds__(256) void gemm_bt(
    const unsigned short* __restrict__ A,   // [8192,1024] bf16
    const unsigned short* __restrict__ B,   // [4096,1024] bf16
    const float* __restrict__ gamma,        // [2048]
    void* __restrict__ Cv)                  // [8192,4096] fp32 or bf16
{
    __shared__ unsigned short sA[128 * 32];  // 8 KB
    __shared__ unsigned short sB[128 * 32];  // 8 KB

    const int tid  = threadIdx.x;
    const int lane = tid & 63;
    const int wave = tid >> 6;
    const int quad = lane >> 4;
    const int m16  = lane & 15;
    const int wm = (wave >> 1) << 6;   // 0 or 64
    const int wn = (wave & 1) << 6;

    const int rowA0 = blockIdx.x * 128;
    const int rowB0 = blockIdx.y * 128;

    // staging map: LDS slot e0 = tid*8 (forced by global_load_lds lane ordering).
    // LDS (row r, group gs) holds global (row r, group gs ^ ((r>>1)&3)).
    const int e0 = tid * 8;
    const int r0 = e0 >> 5;            // row in tile (BK=32)
    const int gs = (e0 >> 3) & 3;
    const int k0 = (gs ^ ((r0 >> 1) & 3)) * 8;   // swizzled global k offset
    const int r1 = r0 + 64;            // second half (same (r>>1)&3 mod 4)

    const unsigned short* a0 = A + (size_t)(rowA0 + r0) * D_DIM + k0;
    const unsigned short* a1 = A + (size_t)(rowA0 + r1) * D_DIM + k0;
    const unsigned short* b0 = B + (size_t)(rowB0 + r0) * D_DIM + k0;
    const unsigned short* b1 = B + (size_t)(rowB0 + r1) * D_DIM + k0;
    unsigned short* la0 = &sA[e0];
    unsigned short* la1 = &sA[e0 + 2048];
    unsigned short* lb0 = &sB[e0];
    unsigned short* lb1 = &sB[e0 + 2048];

    // reader swizzle: row = wm + i*16 + m16 -> (row>>1)&3 == (m16>>1)&3
    const int grp8 = (quad ^ ((m16 >> 1) & 3)) * 8;

    f32x4 acc[4][4];
#pragma unroll
    for (int i = 0; i < 4; i++)
#pragma unroll
        for (int j = 0; j < 4; j++) acc[i][j] = (f32x4)(0.0f);

    for (int kt = 0; kt < D_DIM; kt += 32) {
        __syncthreads();                       // prev-tile reads done
        gl_lds16(a0 + kt, la0);
        gl_lds16(a1 + kt, la1);
        gl_lds16(b0 + kt, lb0);
        gl_lds16(b1 + kt, lb1);
        __syncthreads();                       // staging visible (vmcnt drained)

        bf16x8 af[4], bfr[4];
#pragma unroll
        for (int i = 0; i < 4; i++)
            af[i] = *(const bf16x8*)&sA[(wm + i * 16 + m16) * 32 + grp8];
#pragma unroll
        for (int i = 0; i < 4; i++)
            bfr[i] = *(const bf16x8*)&sB[(wn + i * 16 + m16) * 32 + grp8];

#pragma unroll
        for (int mi = 0; mi < 4; mi++)
#pragma unroll
            for (int ni = 0; ni < 4; ni++)
                acc[mi][ni] = __builtin_amdgcn_mfma_f32_16x16x32_bf16(
                    af[mi], bfr[ni], acc[mi][ni], 0, 0, 0);
    }

    // epilogue: C/D layout col=lane&15, row=quad*4+reg
    float* Cf = (float*)Cv;
    unsigned short* Cb = (unsigned short*)Cv;
#pragma unroll
    for (int ni = 0; ni < 4; ni++) {
        const int col = rowB0 + wn + ni * 16 + m16;
        const float g = gamma[col & (H_DIM - 1)];
#pragma unroll
        for (int mi = 0; mi < 4; mi++) {
            const int row0 = rowA0 + wm + mi * 16 + quad * 4;
#pragma unroll
            for (int r = 0; r < 4; r++) {
                float val = acc[mi][ni][r] * g;
                if (BF16OUT)
                    Cb[(size_t)(row0 + r) * N_DIM + col] = f2bf(val);
                else
                    Cf[(size_t)(row0 + r) * N_DIM + col] = val;
            }
        }
    }
}

// ---------------- kernel 4a: chunk-local end states (zero init), 2 channels/thread ----------------

template <bool BF16IN>
__global__ void scanA(const void* __restrict__ v,        // [T, 4096] bf16 or fp32
                      const float* __restrict__ pa, const float* __restrict__ pb,
                      float* __restrict__ E)             // [NCH][2][H]
{
    int h2 = (blockIdx.x * 256 + threadIdx.x) * 2;   // 0..2046, even
    int c = blockIdx.y;                               // 0..NCH-1
    float2 a = *(const float2*)(pa + h2);
    float2 b = *(const float2*)(pb + h2);
    float h1x = 0.f, h2x = 0.f, h1y = 0.f, h2y = 0.f;
#pragma unroll 8
    for (int t = 0; t < CHUNK; t++) {
        size_t row = (size_t)(c * CHUNK + t) * N_DIM;
        float v1x, v1y, v2x, v2y;
        if (BF16IN) {
            ushort2 u1 = *((const ushort2*)((const unsigned short*)v + row + h2));
            ushort2 u2 = *((const ushort2*)((const unsigned short*)v + row + H_DIM + h2));
            v1x = bf2f(u1.x); v1y = bf2f(u1.y); v2x = bf2f(u2.x); v2y = bf2f(u2.y);
        } else {
            float2 f1 = *((const float2*)((const float*)v + row + h2));
            float2 f2 = *((const float2*)((const float*)v + row + H_DIM + h2));
            v1x = f1.x; v1y = f1.y; v2x = f2.x; v2y = f2.y;
        }
        float n1x = a.x * h1x - b.x * h2x + v1x;
        float n2x = a.x * h2x + b.x * h1x + v2x;
        float n1y = a.y * h1y - b.y * h2y + v1y;
        float n2y = a.y * h2y + b.y * h1y + v2y;
        h1x = n1x; h2x = n2x; h1y = n1y; h2y = n2y;
    }
    *(float2*)(E + (size_t)c * N_DIM + h2)         = make_float2(h1x, h1y);
    *(float2*)(E + (size_t)c * N_DIM + H_DIM + h2) = make_float2(h2x, h2y);
}

// ---------------- kernel 4b: scan carries across chunks ----------------

__global__ void scanB(const float* __restrict__ pa, const float* __restrict__ pb,
                      const float* __restrict__ E, float* __restrict__ P) {
    int h = blockIdx.x * 256 + threadIdx.x;
    float a = pa[h], b = pb[h];
    float wr = a, wi = b;                 // w^CHUNK via 6 complex squarings
#pragma unroll
    for (int i = 0; i < 6; i++) {
        float nr = wr * wr - wi * wi;
        float ni = 2.f * wr * wi;
        wr = nr; wi = ni;
    }
    float p1 = 0.f, p2 = 0.f;
#pragma unroll 4
    for (int c = 0; c < NCH; c++) {
        P[(size_t)c * N_DIM + h]         = p1;
        P[(size_t)c * N_DIM + H_DIM + h] = p2;
        float e1 = E[(size_t)c * N_DIM + h];
        float e2 = E[(size_t)c * N_DIM + H_DIM + h];
        float n1 = wr * p1 - wi * p2 + e1;
        float n2 = wr * p2 + wi * p1 + e2;
        p1 = n1; p2 = n2;
    }
}

// ---------------- kernel 4c: final scan with carry-in ----------------

template <bool BF16IN>
__global__ void scanC(const void* __restrict__ v,        // bf16 (ws) or fp32 (== out)
                      float* __restrict__ out,
                      const float* __restrict__ pa, const float* __restrict__ pb,
                      const float* __restrict__ P) {
    int h2 = (blockIdx.x * 256 + threadIdx.x) * 2;
    int c = blockIdx.y;
    float2 a = *(const float2*)(pa + h2);
    float2 b = *(const float2*)(pb + h2);
    float2 p1 = *(const float2*)(P + (size_t)c * N_DIM + h2);
    float2 p2 = *(const float2*)(P + (size_t)c * N_DIM + H_DIM + h2);
    float h1x = p1.x, h1y = p1.y, h2x = p2.x, h2y = p2.y;
#pragma unroll 8
    for (int t = 0; t < CHUNK; t++) {
        size_t row = (size_t)(c * CHUNK + t) * N_DIM;
        float v1x, v1y, v2x, v2y;
        if (BF16IN) {
            ushort2 u1 = *((const ushort2*)((const unsigned short*)v + row + h2));
            ushort2 u2 = *((const ushort2*)((const unsigned short*)v + row + H_DIM + h2));
            v1x = bf2f(u1.x); v1y = bf2f(u1.y); v2x = bf2f(u2.x); v2y = bf2f(u2.y);
        } else {
            float2 f1 = *((const float2*)((const float*)v + row + h2));
            float2 f2 = *((const float2*)((const float*)v + row + H_DIM + h2));
            v1x = f1.x; v1y = f1.y; v2x = f2.x; v2y = f2.y;
        }
        float n1x = a.x * h1x - b.x * h2x + v1x;
        float n2x = a.x * h2x + b.x * h1x + v2x;
        float n1y = a.y * h1y - b.y * h2y + v1y;
        float n2y = a.y * h2y + b.y * h1y + v2y;
        h1x = n1x; h2x = n2x; h1y = n1y; h2y = n2y;
        *(float2*)(out + row + h2)         = make_float2(h1x, h1y);
        *(float2*)(out + row + H_DIM + h2) = make_float2(h2x, h2y);
    }
}

// ---------------- launcher ----------------

extern "C" void kernel_launch(void* const* d_in, const int* in_sizes, int n_in,
                              void* d_out, int out_size, void* d_ws, size_t ws_size,
                              hipStream_t stream) {
    const float* x     = (const float*)d_in[0];   // [T, D]
    const float* lamda = (const float*)d_in[1];   // [H]
    const float* theta = (const float*)d_in[2];   // [H]
    const float* B1    = (const float*)d_in[3];   // [H, D]
    const float* B2    = (const float*)d_in[4];   // [H, D]
    float* out = (float*)d_out;                   // [T, 2H]

    char* ws = (char*)d_ws;
    unsigned short* xb = (unsigned short*)ws;                              // 16 MB
    unsigned short* Bb = (unsigned short*)(ws + (size_t)16 * 1024 * 1024); // 8 MB
    float* pa = (float*)(ws + (size_t)24 * 1024 * 1024);
    float* pb = pa + H_DIM;
    float* pg = pb + H_DIM;
    float* E  = pg + H_DIM;                    // NCH*4096 floats = 2 MB
    float* P  = E + (size_t)NCH * N_DIM;       // 2 MB
    // optional bf16 v-buffer at 29 MB (needs 64 MB more)
    unsigned short* vb = (unsigned short*)(ws + (size_t)29 * 1024 * 1024);
    const size_t need_bf16 = (size_t)29 * 1024 * 1024 + (size_t)T_DIM * N_DIM * 2;
    const bool use_bf16 = (ws_size >= need_bf16);

    // 1. params
    hipLaunchKernelGGL(params_kernel, dim3(H_DIM / 256), dim3(256), 0, stream,
                       lamda, theta, pa, pb, pg);
    // 2. converts (single launch)
    {
        int n0 = T_DIM * D_DIM / 4, n1 = H_DIM * D_DIM / 4, n2 = n1;
        int blocks = (n0 + n1 + n2 + 255) / 256;
        hipLaunchKernelGGL(cvt3_kernel, dim3(blocks), dim3(256), 0, stream,
                           (const float4*)x, (ushort4*)xb, n0,
                           (const float4*)B1, (ushort4*)Bb, n1,
                           (const float4*)B2, (ushort4*)(Bb + (size_t)H_DIM * D_DIM), n2);
    }
    // 3. GEMM: v (gamma-scaled) -> bf16 ws buffer (preferred) or fp32 d_out
    void* vptr = use_bf16 ? (void*)vb : (void*)out;
    if (use_bf16)
        gemm_bt<true><<<dim3(T_DIM / 128, N_DIM / 128), dim3(256), 0, stream>>>(xb, Bb, pg, vptr);
    else
        gemm_bt<false><<<dim3(T_DIM / 128, N_DIM / 128), dim3(256), 0, stream>>>(xb, Bb, pg, vptr);
    // 4. chunked scan
    dim3 sgrid(H_DIM / 2 / 256, NCH);
    if (use_bf16) {
        scanA<true><<<sgrid, dim3(256), 0, stream>>>(vptr, pa, pb, E);
    } else {
        scanA<false><<<sgrid, dim3(256), 0, stream>>>(vptr, pa, pb, E);
    }
    hipLaunchKernelGGL(scanB, dim3(H_DIM / 256), dim3(256), 0, stream, pa, pb, E, P);
    if (use_bf16) {
        scanC<true><<<sgrid, dim3(256), 0, stream>>>(vptr, out, pa, pb, P);
    } else {
        scanC<false><<<sgrid, dim3(256), 0, stream>>>(vptr, out, pa, pb, P);
    }
}